// Round 1
// baseline (1024.697 us; speedup 1.0000x reference)
//
#include <hip/hip_runtime.h>

// ---------------------------------------------------------------------------
// Problem: B=4, N=16384, DIM=512, HEADS=8, DHEAD=64, window=128
//   q = LN(y@Wq^T)*gq+bq ; k = LN(x@Wk^T)*gk+bk ; v = x@Wv^T
//   per (window,head): attn = softmax(q k^T / 8) ; ctx = attn v
//   y_new = y + ctx@Wout^T + bout
// Outputs: y_new [4,16384,512] fp32 then attn [512,8,128,128] fp32.
// ---------------------------------------------------------------------------

typedef __attribute__((ext_vector_type(8))) short short8;     // 8 bf16 (4 VGPR)
typedef __attribute__((ext_vector_type(4))) float f32x4;      // MFMA C/D
typedef __attribute__((ext_vector_type(4))) unsigned short us4;
typedef __attribute__((ext_vector_type(8))) unsigned short us8;
typedef __attribute__((ext_vector_type(4))) float fv4;

__device__ __forceinline__ unsigned short f2bf(float f) {
  unsigned u = __builtin_bit_cast(unsigned, f);
  u += 0x7fffu + ((u >> 16) & 1u);          // RNE
  return (unsigned short)(u >> 16);
}
__device__ __forceinline__ float bf2f(unsigned short h) {
  unsigned u = ((unsigned)h) << 16;
  return __builtin_bit_cast(float, u);
}

// ---------------------------------------------------------------------------
// fp32 -> bf16 convert (vectorized, 4 elems/thread)
// ---------------------------------------------------------------------------
__global__ __launch_bounds__(256) void cvt_kernel(const float* __restrict__ src,
                                                  unsigned short* __restrict__ dst,
                                                  int n4) {
  int i = blockIdx.x * 256 + threadIdx.x;
  if (i >= n4) return;
  fv4 f = *(const fv4*)(src + (size_t)i * 4);
  us4 o;
  o[0] = f2bf(f[0]); o[1] = f2bf(f[1]); o[2] = f2bf(f[2]); o[3] = f2bf(f[3]);
  *(us4*)(dst + (size_t)i * 4) = o;
}

// ---------------------------------------------------------------------------
// BT-GEMM: C[m][n] = sum_k A[m][k] * Bw[n][k],  M x 512 x 512, bf16 inputs.
// 128x128 block tile, BK=32, 256 threads (4 waves, 64x64 wave tiles).
// Staging via global_load_lds width=16 with XOR-swizzled 16B chunks so
// fragment ds_read_b128 is 2-way (free) instead of 8-way conflicted.
// FINAL=0: bf16 out.  FINAL=1: fp32 out = acc + yres + bias (fused epilogue).
// ---------------------------------------------------------------------------
template <int FINAL>
__global__ __launch_bounds__(256) void gemm_bt(const unsigned short* __restrict__ A,
                                               const unsigned short* __restrict__ Bw,
                                               unsigned short* __restrict__ Cb,
                                               float* __restrict__ Cf,
                                               const float* __restrict__ yres,
                                               const float* __restrict__ bias) {
  __shared__ __align__(16) unsigned short As[128 * 32];
  __shared__ __align__(16) unsigned short Bs[128 * 32];
  const int tid = threadIdx.x;
  const int lane = tid & 63;
  const int wv = tid >> 6;
  const int quad = lane >> 4;
  const int l16 = lane & 15;
  const size_t m0 = (size_t)blockIdx.x * 128;
  const int n0 = blockIdx.y * 128;
  const int wm = (wv >> 1) * 64;
  const int wn = (wv & 1) * 64;

  f32x4 acc[4][4];
#pragma unroll
  for (int i = 0; i < 4; i++)
#pragma unroll
    for (int j = 0; j < 4; j++) acc[i][j] = (f32x4){0.f, 0.f, 0.f, 0.f};

  // staging map: lds chunk c = i*256+tid holds global chunk (m = c>>2,
  // kc = (c&3) ^ ((m>>2)&3))  -> fragment reads become 2-way-bank-free
  int ma[2], koff[2];
#pragma unroll
  for (int i = 0; i < 2; i++) {
    int c = i * 256 + tid;
    int m = c >> 2;
    int kc = (c & 3) ^ ((m >> 2) & 3);
    ma[i] = m;
    koff[i] = kc * 16;
  }
  const char* Ab = (const char*)A;
  const char* Bb = (const char*)Bw;
  char* AsB = (char*)As;
  char* BsB = (char*)Bs;

  for (int ks = 0; ks < 512; ks += 32) {
#pragma unroll
    for (int i = 0; i < 2; i++) {
      const char* ga = Ab + ((m0 + (size_t)ma[i]) << 10) + ks * 2 + koff[i];
      const char* gb = Bb + (((size_t)(n0 + ma[i])) << 10) + ks * 2 + koff[i];
      __builtin_amdgcn_global_load_lds(
          (const __attribute__((address_space(1))) unsigned int*)ga,
          (__attribute__((address_space(3))) unsigned int*)(AsB + i * 4096 + wv * 1024),
          16, 0, 0);
      __builtin_amdgcn_global_load_lds(
          (const __attribute__((address_space(1))) unsigned int*)gb,
          (__attribute__((address_space(3))) unsigned int*)(BsB + i * 4096 + wv * 1024),
          16, 0, 0);
    }
    __syncthreads();  // drains vmcnt (DMA deposits visible), syncs waves

    short8 af[4], bf[4];
#pragma unroll
    for (int t = 0; t < 4; t++) {
      int m = wm + t * 16 + l16;
      af[t] = *(const short8*)&As[m * 32 + ((quad ^ ((m >> 2) & 3)) * 8)];
      int n = wn + t * 16 + l16;
      bf[t] = *(const short8*)&Bs[n * 32 + ((quad ^ ((n >> 2) & 3)) * 8)];
    }
#pragma unroll
    for (int mt = 0; mt < 4; mt++)
#pragma unroll
      for (int nt = 0; nt < 4; nt++)
        acc[mt][nt] =
            __builtin_amdgcn_mfma_f32_16x16x32_bf16(af[mt], bf[nt], acc[mt][nt], 0, 0, 0);
    __syncthreads();  // all reads done before next stage overwrites
  }

  // epilogue; C/D layout: col = lane&15, row = quad*4 + reg
#pragma unroll
  for (int mt = 0; mt < 4; mt++) {
    size_t mrow = m0 + wm + mt * 16 + quad * 4;
#pragma unroll
    for (int nt = 0; nt < 4; nt++) {
      int n = n0 + wn + nt * 16 + l16;
#pragma unroll
      for (int r = 0; r < 4; r++) {
        size_t idx = (mrow + r) * 512 + n;
        if (FINAL) {
          Cf[idx] = acc[mt][nt][r] + yres[idx] + bias[n];
        } else {
          Cb[idx] = f2bf(acc[mt][nt][r]);
        }
      }
    }
  }
}

// ---------------------------------------------------------------------------
// In-place LayerNorm over rows of 512 bf16. One wave per row (8 elems/lane).
// ---------------------------------------------------------------------------
__global__ __launch_bounds__(256) void ln_rows(unsigned short* __restrict__ t,
                                               const float* __restrict__ g,
                                               const float* __restrict__ b) {
  size_t row = (size_t)blockIdx.x * 4 + (threadIdx.x >> 6);
  int lane = threadIdx.x & 63;
  unsigned short* p = t + row * 512 + lane * 8;
  us8 raw = *(const us8*)p;
  float v[8];
#pragma unroll
  for (int i = 0; i < 8; i++) v[i] = bf2f(raw[i]);
  float s = 0.f;
#pragma unroll
  for (int i = 0; i < 8; i++) s += v[i];
#pragma unroll
  for (int off = 32; off; off >>= 1) s += __shfl_xor(s, off);
  float mean = s * (1.0f / 512.0f);
  float qs = 0.f;
#pragma unroll
  for (int i = 0; i < 8; i++) {
    float d = v[i] - mean;
    qs += d * d;
  }
#pragma unroll
  for (int off = 32; off; off >>= 1) qs += __shfl_xor(qs, off);
  float rstd = rsqrtf(qs * (1.0f / 512.0f) + 1e-5f);
  const float* gp = g + lane * 8;
  const float* bp = b + lane * 8;
  us8 o;
#pragma unroll
  for (int i = 0; i < 8; i++) o[i] = f2bf((v[i] - mean) * rstd * gp[i] + bp[i]);
  *(us8*)p = o;
}

// ---------------------------------------------------------------------------
// Attention: one WG per (head h = blockIdx.x, window bw = blockIdx.y).
// 256 threads = 4 waves; wave handles a 32-row strip of the 128x128 score.
// QK^T fragments loaded directly from global (16B aligned). Softmax in-reg
// with 16-lane shfl_xor reductions. P -> LDS (bf16, swizzled) for A-layout;
// v staged transposed (vT) in LDS for B-layout; PV via MFMA.
// ---------------------------------------------------------------------------
__global__ __launch_bounds__(256) void attn_kernel(const unsigned short* __restrict__ q,
                                                   const unsigned short* __restrict__ kmat,
                                                   const unsigned short* __restrict__ v,
                                                   float* __restrict__ attn_out,
                                                   unsigned short* __restrict__ ctx) {
  __shared__ __align__(16) unsigned short vT[64 * 128];   // [d][t], swizzled 16B chunks
  __shared__ __align__(16) unsigned short Ps[128 * 128];  // [i][j], swizzled 16B chunks
  const int h = blockIdx.x;
  const int bw = blockIdx.y;
  const int tb = bw * 128;  // global token base of this window
  const int tid = threadIdx.x;
  const int lane = tid & 63;
  const int wv = tid >> 6;
  const int quad = lane >> 4;
  const int l16 = lane & 15;
  const int hoff = h * 64;

  // ---- stage v transposed: vT[d][t] = v[tb+t][hoff+d]
#pragma unroll
  for (int it = 0; it < 8; it++) {
    int idx = (it * 256 + tid) * 4;  // 0..8188, 4 consecutive d per thread
    int t = idx >> 6;
    int d = idx & 63;
    us4 val = *(const us4*)&v[(size_t)(tb + t) * 512 + hoff + d];
#pragma unroll
    for (int j = 0; j < 4; j++) {
      int dd = d + j;
      int cp = (t >> 3) ^ (dd & 15);
      vT[dd * 128 + cp * 8 + (t & 7)] = val[j];
    }
  }

  // ---- S = q k^T  (strip rows = wv*32 .. +31)
  f32x4 acc[2][8];
#pragma unroll
  for (int mi = 0; mi < 2; mi++)
#pragma unroll
    for (int ni = 0; ni < 8; ni++) acc[mi][ni] = (f32x4){0.f, 0.f, 0.f, 0.f};

  short8 aq[2][2];
#pragma unroll
  for (int mi = 0; mi < 2; mi++) {
    int tok = tb + wv * 32 + mi * 16 + l16;
#pragma unroll
    for (int kk = 0; kk < 2; kk++)
      aq[mi][kk] = *(const short8*)&q[(size_t)tok * 512 + hoff + kk * 32 + quad * 8];
  }
#pragma unroll
  for (int ni = 0; ni < 8; ni++) {
    int ktok = tb + ni * 16 + l16;
    short8 bk0 = *(const short8*)&kmat[(size_t)ktok * 512 + hoff + quad * 8];
    short8 bk1 = *(const short8*)&kmat[(size_t)ktok * 512 + hoff + 32 + quad * 8];
#pragma unroll
    for (int mi = 0; mi < 2; mi++) {
      acc[mi][ni] = __builtin_amdgcn_mfma_f32_16x16x32_bf16(aq[mi][0], bk0, acc[mi][ni], 0, 0, 0);
      acc[mi][ni] = __builtin_amdgcn_mfma_f32_16x16x32_bf16(aq[mi][1], bk1, acc[mi][ni], 0, 0, 0);
    }
  }

  // ---- softmax over rows (cols split across 16 lanes x 8 ni tiles)
  const float c1 = 0.125f * 1.44269504088896f;  // scale * log2(e)
  size_t abase = ((size_t)(bw * 8 + h)) << 14;  // *16384
#pragma unroll
  for (int mi = 0; mi < 2; mi++) {
#pragma unroll
    for (int r = 0; r < 4; r++) {
      float mx = acc[mi][0][r];
#pragma unroll
      for (int ni = 1; ni < 8; ni++) mx = fmaxf(mx, acc[mi][ni][r]);
      mx = fmaxf(mx, __shfl_xor(mx, 1));
      mx = fmaxf(mx, __shfl_xor(mx, 2));
      mx = fmaxf(mx, __shfl_xor(mx, 4));
      mx = fmaxf(mx, __shfl_xor(mx, 8));
      float pv[8];
      float sum = 0.f;
#pragma unroll
      for (int ni = 0; ni < 8; ni++) {
        pv[ni] = __expf((acc[mi][ni][r] - mx) * 0.125f);
        sum += pv[ni];
      }
      sum += __shfl_xor(sum, 1);
      sum += __shfl_xor(sum, 2);
      sum += __shfl_xor(sum, 4);
      sum += __shfl_xor(sum, 8);
      float inv = 1.0f / sum;
      int i = wv * 32 + mi * 16 + quad * 4 + r;
#pragma unroll
      for (int ni = 0; ni < 8; ni++) {
        float p = pv[ni] * inv;
        int j = ni * 16 + l16;
        attn_out[abase + (size_t)i * 128 + j] = p;  // attn output (fp32)
        int cp = (j >> 3) ^ (i & 15);
        Ps[i * 128 + cp * 8 + (j & 7)] = f2bf(p);
      }
    }
  }
  (void)c1;
  __syncthreads();  // Ps + vT ready for all waves

  // ---- ctx = P @ v   (strip rows 32/wave, 64 dims = 4 n-tiles, K=128)
  f32x4 o[2][4];
#pragma unroll
  for (int mi = 0; mi < 2; mi++)
#pragma unroll
    for (int nt = 0; nt < 4; nt++) o[mi][nt] = (f32x4){0.f, 0.f, 0.f, 0.f};

#pragma unroll
  for (int ks = 0; ks < 4; ks++) {
    short8 bfr[4];
#pragma unroll
    for (int nt = 0; nt < 4; nt++) {
      int d = nt * 16 + l16;
      int cp = (ks * 4 + quad) ^ (d & 15);
      bfr[nt] = *(const short8*)&vT[d * 128 + cp * 8];
    }
#pragma unroll
    for (int mi = 0; mi < 2; mi++) {
      int i = wv * 32 + mi * 16 + l16;
      int cp = (ks * 4 + quad) ^ (i & 15);
      short8 afr = *(const short8*)&Ps[i * 128 + cp * 8];
#pragma unroll
      for (int nt = 0; nt < 4; nt++)
        o[mi][nt] = __builtin_amdgcn_mfma_f32_16x16x32_bf16(afr, bfr[nt], o[mi][nt], 0, 0, 0);
    }
  }
#pragma unroll
  for (int mi = 0; mi < 2; mi++)
#pragma unroll
    for (int nt = 0; nt < 4; nt++)
#pragma unroll
      for (int r = 0; r < 4; r++) {
        int tok = tb + wv * 32 + mi * 16 + quad * 4 + r;
        int d = nt * 16 + l16;
        ctx[(size_t)tok * 512 + hoff + d] = f2bf(o[mi][nt][r]);
      }
}

// ---------------------------------------------------------------------------
extern "C" void kernel_launch(void* const* d_in, const int* in_sizes, int n_in,
                              void* d_out, int out_size, void* d_ws, size_t ws_size,
                              hipStream_t stream) {
  const float* x = (const float*)d_in[0];
  const float* y = (const float*)d_in[1];
  const float* Wq = (const float*)d_in[2];
  const float* gq = (const float*)d_in[3];
  const float* bq = (const float*)d_in[4];
  const float* Wk = (const float*)d_in[5];
  const float* gk = (const float*)d_in[6];
  const float* bk = (const float*)d_in[7];
  const float* Wv = (const float*)d_in[8];
  const float* Wout = (const float*)d_in[9];
  const float* bout = (const float*)d_in[10];
  float* out = (float*)d_out;

  // workspace layout (bytes)
  char* ws = (char*)d_ws;
  const size_t W = 524288;     // 512*512 bf16
  const size_t T = 67108864;   // 65536*512 bf16
  unsigned short* WQB = (unsigned short*)(ws);
  unsigned short* WKB = (unsigned short*)(ws + W);
  unsigned short* WVB = (unsigned short*)(ws + 2 * W);
  unsigned short* WOB = (unsigned short*)(ws + 3 * W);
  unsigned short* XB = (unsigned short*)(ws + 4 * W);
  unsigned short* YB = (unsigned short*)(ws + 4 * W + T);  // y bf16; reused as ctx later
  unsigned short* Q = (unsigned short*)(ws + 4 * W + 2 * T);
  unsigned short* Kb = (unsigned short*)(ws + 4 * W + 3 * T);
  unsigned short* Vb = (unsigned short*)(ws + 4 * W + 4 * T);
  unsigned short* CTX = YB;  // alias: yb dead after q-projection GEMM

  // bf16 conversions
  cvt_kernel<<<256, 256, 0, stream>>>(Wq, WQB, 65536);
  cvt_kernel<<<256, 256, 0, stream>>>(Wk, WKB, 65536);
  cvt_kernel<<<256, 256, 0, stream>>>(Wv, WVB, 65536);
  cvt_kernel<<<256, 256, 0, stream>>>(Wout, WOB, 65536);
  cvt_kernel<<<32768, 256, 0, stream>>>(x, XB, 8388608);
  cvt_kernel<<<32768, 256, 0, stream>>>(y, YB, 8388608);

  // projections (M=65536, N=512, K=512)
  dim3 gg(512, 4);
  gemm_bt<0><<<gg, 256, 0, stream>>>(YB, WQB, Q, nullptr, nullptr, nullptr);
  gemm_bt<0><<<gg, 256, 0, stream>>>(XB, WKB, Kb, nullptr, nullptr, nullptr);
  gemm_bt<0><<<gg, 256, 0, stream>>>(XB, WVB, Vb, nullptr, nullptr, nullptr);

  // layernorms (in-place on bf16)
  ln_rows<<<16384, 256, 0, stream>>>(Q, gq, bq);
  ln_rows<<<16384, 256, 0, stream>>>(Kb, gk, bk);

  // attention: attn -> d_out (after y_new region), ctx -> ws
  attn_kernel<<<dim3(8, 512), 256, 0, stream>>>(Q, Kb, Vb, out + 33554432, CTX);

  // y_new = y + ctx @ Wout^T + bout
  gemm_bt<1><<<gg, 256, 0, stream>>>(CTX, WOB, nullptr, out, y, bout);
}